// Round 6
// baseline (82.106 us; speedup 1.0000x reference)
//
#include <hip/hip_runtime.h>

#define NB 32
#define NA 3
#define GD 52
#define GG 2704          // 52*52
#define NC 80
#define CHN 85           // NC + 5
#define TILE 52          // one grid row per block
#define TPP 52           // tiles per (b,a) plane
#define NBLK (NB * NA * TPP)   // 4992
#define NPAD 5120        // padded per-plane stride in ws (floats)
#define NXQ 1105         // CHN*13 x-quads per block
#define NTQ 1040         // TILE*NC/4 tcls quads per block
#define LXW 4420         // TILE*CHN words

// sigmoid via hardware rcp (z in [-7,7] here; rel err ~1e-7 ok)
__device__ __forceinline__ float sigm_u(float u) { return __builtin_amdgcn_rcpf(u); }

__global__ __launch_bounds__(256) void yolo_main(
    const float* __restrict__ x,
    const float* __restrict__ tx, const float* __restrict__ ty,
    const float* __restrict__ tw, const float* __restrict__ th,
    const float* __restrict__ tconf, const float* __restrict__ tcls,
    const float* __restrict__ sw1,
    const int* __restrict__ om, const int* __restrict__ nm,
    const int* __restrict__ imgdim,
    float* __restrict__ out,
    float* __restrict__ partials,      // [4][NPAD]; may be null
    double* __restrict__ accD)         // fallback padded atomics
{
    __shared__ float lx[LXW];          // transformed tile in OUTPUT order: [s][ch]
    __shared__ float laux[8][TILE];    // tx,ty,tw,th,tconf,sw,om,nm
    __shared__ float lred[4][4];

    const int tid   = threadIdx.x;
    const int bid   = blockIdx.x;
    const int tile  = bid % TPP;       // grid row gy
    const int plane = bid / TPP;
    const int a     = plane % NA;
    const int b     = plane / NA;
    const int s0    = tile * TILE;

    int iv = imgdim[0];
    float imgf = (iv > 0 && iv < 65536) ? (float)iv : __int_as_float(iv);
    const float stride = imgf / (float)GD;
    const float aw = (a == 0) ? 10.0f : ((a == 1) ? 16.0f : 33.0f);
    const float ah = (a == 0) ? 13.0f : ((a == 1) ? 30.0f : 23.0f);
    const float gyf = (float)tile;

    const long paux = (long)(plane * GG + s0);
    const float* xb = x + ((long)b * (NA * CHN) + a * CHN) * GG + s0;
    const float* tb = tcls + paux * NC;

    // ---- B: aux planes (coalesced 52-runs over 416 thread-slots) ----
    float nobj_p = 0.0f, nnob_p = 0.0f;
    for (int u = tid; u < 8 * TILE; u += 256) {
        int pl = u / TILE, s = u - pl * TILE;
        float v;
        switch (pl) {
            case 0: v = tx[paux + s]; break;
            case 1: v = ty[paux + s]; break;
            case 2: v = tw[paux + s]; break;
            case 3: v = th[paux + s]; break;
            case 4: v = tconf[paux + s]; break;
            case 5: v = sw1[paux + s]; break;
            case 6: v = (float)om[paux + s]; nobj_p += v; break;
            default: v = (float)nm[paux + s]; nnob_p += v; break;
        }
        laux[pl][s] = v;
    }

    // ---- A: issue ALL x float4 loads NOW (independent of laux);
    //         latency hides under barrier + tcls issue ----
    float4 xr[5];
    #pragma unroll
    for (int k = 0; k < 5; ++k) {
        int q = tid + 256 * k;
        if (q < NXQ) {
            int ch = q / 13;
            int sq = (q - ch * 13) * 4;
            xr[k] = *(const float4*)(xb + ch * GG + sq);
        }
    }
    __syncthreads();

    // ---- C: issue om-gated tcls float4 loads; latency hides under D ----
    float4 tr[5]; float gk[5];
    #pragma unroll
    for (int k = 0; k < 5; ++k) {
        gk[k] = 0.0f;
        int q = tid + 256 * k;
        if (q < NTQ) {
            int s = q / 20;
            int c4 = (q - s * 20) * 4;
            float g = laux[6][s];
            gk[k] = g;
            if (g != 0.0f) tr[k] = *(const float4*)(tb + s * NC + c4);
        }
    }

    float s_obj = 0.f, s_cn = 0.f, s_cl = 0.f;

    // ---- D: transform + losses from prefetched regs; flat LDS store ----
    #pragma unroll
    for (int k = 0; k < 5; ++k) {
        int q = tid + 256 * k;
        if (q >= NXQ) break;
        int ch = q / 13;
        int sq = (q - ch * 13) * 4;
        float vv[4] = { xr[k].x, xr[k].y, xr[k].z, xr[k].w };
        int base = sq * CHN + ch;
        if (ch >= 5) {
            #pragma unroll
            for (int j = 0; j < 4; ++j) {
                float u = 1.0f + __expf(-vv[j]);
                lx[base + j * CHN] = sigm_u(u);
            }
        } else if (ch == 0) {
            #pragma unroll
            for (int j = 0; j < 4; ++j) {
                int s = sq + j;
                float p = sigm_u(1.0f + __expf(-vv[j]));
                float d = p - laux[0][s];
                s_obj = fmaf(laux[6][s] * laux[5][s], d * d, s_obj);
                lx[s * CHN + 0] = (p + (float)s) * stride;   // gx = s
            }
        } else if (ch == 1) {
            #pragma unroll
            for (int j = 0; j < 4; ++j) {
                int s = sq + j;
                float p = sigm_u(1.0f + __expf(-vv[j]));
                float d = p - laux[1][s];
                s_obj = fmaf(laux[6][s] * laux[5][s], d * d, s_obj);
                lx[s * CHN + 1] = (p + gyf) * stride;        // gy = tile
            }
        } else if (ch == 2) {
            #pragma unroll
            for (int j = 0; j < 4; ++j) {
                int s = sq + j;
                float d = vv[j] - laux[2][s];
                s_obj = fmaf(laux[6][s] * laux[5][s], d * d, s_obj);
                lx[s * CHN + 2] = __expf(vv[j]) * aw;
            }
        } else if (ch == 3) {
            #pragma unroll
            for (int j = 0; j < 4; ++j) {
                int s = sq + j;
                float d = vv[j] - laux[3][s];
                s_obj = fmaf(laux[6][s] * laux[5][s], d * d, s_obj);
                lx[s * CHN + 3] = __expf(vv[j]) * ah;
            }
        } else { // ch == 4: conf BCE from logits: ln(u) + (1-t)*z, u = 1+e^-z
            #pragma unroll
            for (int j = 0; j < 4; ++j) {
                int s = sq + j;
                float z = vv[j];
                float u = 1.0f + __expf(-z);
                float p = sigm_u(u);
                float t = laux[4][s];
                float bb = fmaf(1.0f - t, z, __logf(u));
                s_obj = fmaf(laux[6][s] * laux[5][s], bb, s_obj);
                s_cn  = fmaf(laux[7][s], bb, s_cn);
                lx[s * CHN + 4] = p;
            }
        }
    }
    __syncthreads();

    // ---- F: conflict-free ds_read_b128 + perfectly coalesced global writes ----
    float* ob = out + paux * CHN;
    #pragma unroll
    for (int k = 0; k < 5; ++k) {
        int q = tid + 256 * k;
        if (q < NXQ) {
            float4 w = *(const float4*)&lx[4 * q];
            *(float4*)(ob + 4 * q) = w;
        }
    }

    // ---- G: cls BCE from prefetched tcls + flat lx reads ----
    #pragma unroll
    for (int k = 0; k < 5; ++k) {
        int q = tid + 256 * k;
        if (q < NTQ && gk[k] != 0.0f) {
            int s = q / 20;
            int c4 = (q - s * 20) * 4;
            int base = s * CHN + 5 + c4;
            float tt[4] = { tr[k].x, tr[k].y, tr[k].z, tr[k].w };
            #pragma unroll
            for (int j = 0; j < 4; ++j) {
                float p = lx[base + j];
                s_cl -= fmaf(tt[j], __logf(p), (1.0f - tt[j]) * __logf(1.0f - p));
            }
        }
    }
    // fold cls into the shared /n_obj sum: loss_cls = (s_cl/80)/n_obj
    s_obj = fmaf(s_cl, 0.0125f, s_obj);

    // ---- H: block reduction of 4 values -> one ws slot per block ----
    float vals[4] = { nobj_p, nnob_p, s_obj, s_cn };
    #pragma unroll
    for (int k = 0; k < 4; ++k) {
        float v = vals[k];
        #pragma unroll
        for (int off = 32; off > 0; off >>= 1) v += __shfl_down(v, off, 64);
        vals[k] = v;
    }
    const int wv = tid >> 6, ln = tid & 63;
    if (ln == 0) {
        #pragma unroll
        for (int k = 0; k < 4; ++k) lred[wv][k] = vals[k];
    }
    __syncthreads();
    if (tid == 0) {
        if (partials) {
            #pragma unroll
            for (int k = 0; k < 4; ++k)
                partials[k * NPAD + bid] = lred[0][k] + lred[1][k] + lred[2][k] + lred[3][k];
        } else {
            #pragma unroll
            for (int k = 0; k < 4; ++k) {
                float s = lred[0][k] + lred[1][k] + lred[2][k] + lred[3][k];
                atomicAdd(&accD[k * 8], (double)s);
            }
        }
    }
}

__device__ __forceinline__ void final_loss(const double* t, float* out_loss) {
    double nobj   = fmax(t[0], 1.0);
    double nnoobj = fmax(t[1], 1.0);
    *out_loss = (float)(t[2] / nobj + 100.0 * t[3] / nnoobj);
}

__global__ __launch_bounds__(256) void yolo_reduce(const float* __restrict__ partials,
                                                   float* __restrict__ out_loss)
{
    __shared__ double sred[4];
    const int w = threadIdx.x >> 6, ln = threadIdx.x & 63;
    double s = 0.0;
    for (int i = ln; i < NBLK; i += 64) s += (double)partials[w * NPAD + i];
    #pragma unroll
    for (int off = 32; off > 0; off >>= 1) s += __shfl_down(s, off, 64);
    if (ln == 0) sred[w] = s;
    __syncthreads();
    if (threadIdx.x == 0) final_loss(sred, out_loss);
}

__global__ void yolo_final_atomic(const double* __restrict__ accD, float* __restrict__ out_loss)
{
    double t[4];
    #pragma unroll
    for (int k = 0; k < 4; ++k) t[k] = accD[k * 8];
    final_loss(t, out_loss);
}

extern "C" void kernel_launch(void* const* d_in, const int* in_sizes, int n_in,
                              void* d_out, int out_size, void* d_ws, size_t ws_size,
                              hipStream_t stream)
{
    const float* x     = (const float*)d_in[0];
    const float* tx    = (const float*)d_in[1];
    const float* ty    = (const float*)d_in[2];
    const float* tw    = (const float*)d_in[3];
    const float* th    = (const float*)d_in[4];
    const float* tconf = (const float*)d_in[5];
    const float* tcls  = (const float*)d_in[6];
    const float* sw1   = (const float*)d_in[7];
    const int*   om    = (const int*)d_in[8];
    const int*   nm    = (const int*)d_in[9];
    const int*   img   = (const int*)d_in[10];
    float* out = (float*)d_out;

    const size_t need = (size_t)4 * NPAD * sizeof(float);
    dim3 grid(NBLK);   // 4992 blocks

    if (ws_size >= need) {
        float* partials = (float*)d_ws;
        yolo_main<<<grid, 256, 0, stream>>>(x, tx, ty, tw, th, tconf, tcls, sw1,
                                            om, nm, img, out, partials, nullptr);
        yolo_reduce<<<1, 256, 0, stream>>>(partials, out + (out_size - 1));
    } else {
        double* accD = (double*)d_ws;
        hipMemsetAsync(d_ws, 0, 4 * 8 * sizeof(double), stream);
        yolo_main<<<grid, 256, 0, stream>>>(x, tx, ty, tw, th, tconf, tcls, sw1,
                                            om, nm, img, out, nullptr, accD);
        yolo_final_atomic<<<1, 1, 0, stream>>>(accD, out + (out_size - 1));
    }
}

// Round 8
// 66.507 us; speedup vs baseline: 1.2345x; 1.2345x over previous
//
#include <hip/hip_runtime.h>

#define NB 32
#define NA 3
#define GD 52
#define GG 2704              // 52*52
#define NC 80
#define CHN 85               // NC + 5
#define CPW 16               // cells per wave
#define WPP 169              // waves per plane = GG/CPW
#define NPLANE (NB * NA)     // 96
#define NWAVE (NPLANE * WPP) // 16224
#define WPB 4                // waves per block (256 threads)
#define NBLK (NWAVE / WPB)   // 4056
#define NXQ 340              // CPW*CHN/4 x-quads per wave
#define LXW 1360             // CPW*CHN words per wave
#define AUXW 160             // 10 aux planes * CPW per wave

// sigmoid via hardware rcp (|z| < ~7 here; rel err ~1e-6, validated absmax 0.25)
__device__ __forceinline__ float sigm_u(float u) { return __builtin_amdgcn_rcpf(u); }

__global__ __launch_bounds__(256) void yolo_main(
    const float* __restrict__ x,
    const float* __restrict__ tx, const float* __restrict__ ty,
    const float* __restrict__ tw, const float* __restrict__ th,
    const float* __restrict__ tconf, const float* __restrict__ tcls,
    const float* __restrict__ sw1,
    const int* __restrict__ om, const int* __restrict__ nm,
    const int* __restrict__ imgdim,
    float* __restrict__ out,
    float4* __restrict__ partials,     // [NWAVE]; may be null
    double* __restrict__ accD)         // fallback padded atomics
{
    __shared__ float lx_all[WPB * LXW];    // per-wave transposed tiles
    __shared__ float la_all[WPB * AUXW];   // per-wave aux tables (exec-mask-safe)

    const int tid  = threadIdx.x;
    const int widx = tid >> 6, lane = tid & 63;
    const int wid  = blockIdx.x * WPB + widx;
    const int plane = wid / WPP;
    const int sblk  = wid - plane * WPP;
    const int a = plane % NA, b = plane / NA;
    const int s0 = sblk * CPW;             // 64B-aligned segment per channel
    float* lx = lx_all + widx * LXW;
    float* la = la_all + widx * AUXW;

    int iv = imgdim[0];
    float imgf = (iv > 0 && iv < 65536) ? (float)iv : __int_as_float(iv);
    const float stride = imgf / (float)GD;
    const float aw = (a == 0) ? 10.0f : ((a == 1) ? 16.0f : 33.0f);
    const float ah = (a == 0) ? 13.0f : ((a == 1) ? 30.0f : 23.0f);

    const long pbase = (long)plane * GG + s0;
    const float* xb = x + ((long)b * (NA * CHN) + a * CHN) * GG + s0;
    const float* tb = tcls + pbase * NC;

    // ---- aux: lanes 0-15 load the wave's 16 cells -> wave-local LDS table.
    //      planes: 0:tx 1:ty 2:tw 3:th 4:tconf 5:om*sw 6:nm 7:om 8:gx 9:gy
    float v0 = 0.0f, v1 = 0.0f;
    if (lane < CPW) {
        float vtx = tx[pbase + lane],    vty = ty[pbase + lane];
        float vtw = tw[pbase + lane],    vth = th[pbase + lane];
        float vtc = tconf[pbase + lane], vsw = sw1[pbase + lane];
        float vom = (float)om[pbase + lane], vnm = (float)nm[pbase + lane];
        int gcell = s0 + lane;
        int gyi = gcell / GD;
        la[0 * CPW + lane] = vtx;  la[1 * CPW + lane] = vty;
        la[2 * CPW + lane] = vtw;  la[3 * CPW + lane] = vth;
        la[4 * CPW + lane] = vtc;  la[5 * CPW + lane] = vom * vsw;
        la[6 * CPW + lane] = vnm;  la[7 * CPW + lane] = vom;
        la[8 * CPW + lane] = (float)(gcell - gyi * GD);
        la[9 * CPW + lane] = (float)gyi;
        v0 = vom; v1 = vnm;
    }

    // ---- x prefetch: all 6 quads in flight at once ----
    float4 xr[6];
    #pragma unroll
    for (int k = 0; k < 6; ++k) {
        int q = lane + 64 * k;
        if (q < NXQ) {
            int ch = q >> 2, sq = (q & 3) << 2;   // 4 quads per channel
            xr[k] = *(const float4*)(xb + (long)ch * GG + sq);
        }
    }
    __builtin_amdgcn_wave_barrier();

    // ---- tcls gated prefetch (320 quads = 5*64 exactly); gate from LDS ----
    float4 tr[5]; float gk[5];
    #pragma unroll
    for (int k = 0; k < 5; ++k) {
        int q = lane + 64 * k;
        int s = q / 20, c4 = (q - s * 20) * 4;
        float g = la[7 * CPW + s];
        gk[k] = g;
        if (g != 0.0f) tr[k] = *(const float4*)(tb + s * NC + c4);
    }

    float s_obj = 0.f, s_cn = 0.f, s_cl = 0.f;

    // ---- transform + losses; aux via wave-local LDS (no shuffles in
    //      divergent branches); wave-local lx store, no block barrier ----
    #pragma unroll
    for (int k = 0; k < 6; ++k) {
        int q = lane + 64 * k;
        if (q >= NXQ) continue;
        int ch = q >> 2, sq = (q & 3) << 2;
        float vv[4] = { xr[k].x, xr[k].y, xr[k].z, xr[k].w };
        if (ch >= 5) {
            #pragma unroll
            for (int j = 0; j < 4; ++j)
                lx[(sq + j) * CHN + ch] = sigm_u(1.0f + __expf(-vv[j]));
        } else if (ch == 0) {
            #pragma unroll
            for (int j = 0; j < 4; ++j) {
                int s = sq + j;
                float p = sigm_u(1.0f + __expf(-vv[j]));
                float d = p - la[0 * CPW + s];
                s_obj = fmaf(la[5 * CPW + s], d * d, s_obj);
                lx[s * CHN + 0] = (p + la[8 * CPW + s]) * stride;
            }
        } else if (ch == 1) {
            #pragma unroll
            for (int j = 0; j < 4; ++j) {
                int s = sq + j;
                float p = sigm_u(1.0f + __expf(-vv[j]));
                float d = p - la[1 * CPW + s];
                s_obj = fmaf(la[5 * CPW + s], d * d, s_obj);
                lx[s * CHN + 1] = (p + la[9 * CPW + s]) * stride;
            }
        } else if (ch == 2) {
            #pragma unroll
            for (int j = 0; j < 4; ++j) {
                int s = sq + j;
                float d = vv[j] - la[2 * CPW + s];
                s_obj = fmaf(la[5 * CPW + s], d * d, s_obj);
                lx[s * CHN + 2] = __expf(vv[j]) * aw;
            }
        } else if (ch == 3) {
            #pragma unroll
            for (int j = 0; j < 4; ++j) {
                int s = sq + j;
                float d = vv[j] - la[3 * CPW + s];
                s_obj = fmaf(la[5 * CPW + s], d * d, s_obj);
                lx[s * CHN + 3] = __expf(vv[j]) * ah;
            }
        } else { // ch == 4: conf BCE from logits: ln(u) + (1-t)*z, u = 1+e^-z
            #pragma unroll
            for (int j = 0; j < 4; ++j) {
                int s = sq + j;
                float z = vv[j];
                float u = 1.0f + __expf(-z);
                float p = sigm_u(u);
                float t = la[4 * CPW + s];
                float bb = fmaf(1.0f - t, z, __logf(u));
                s_obj = fmaf(la[5 * CPW + s], bb, s_obj);
                s_cn  = fmaf(la[6 * CPW + s], bb, s_cn);
                lx[s * CHN + 4] = p;
            }
        }
    }
    __builtin_amdgcn_wave_barrier();

    // ---- output: wave-local ds_read_b128 + perfectly coalesced 16B stores ----
    float* ob = out + pbase * CHN;
    #pragma unroll
    for (int k = 0; k < 6; ++k) {
        int q = lane + 64 * k;
        if (q < NXQ) {
            float4 w4 = *(const float4*)&lx[4 * q];
            *(float4*)(ob + 4 * q) = w4;
        }
    }

    // ---- cls BCE from prefetched tcls + wave-local lx reads ----
    #pragma unroll
    for (int k = 0; k < 5; ++k) {
        if (gk[k] != 0.0f) {
            int q = lane + 64 * k;
            int s = q / 20, c4 = (q - s * 20) * 4;
            int base = s * CHN + 5 + c4;
            float tt[4] = { tr[k].x, tr[k].y, tr[k].z, tr[k].w };
            #pragma unroll
            for (int j = 0; j < 4; ++j) {
                float p = lx[base + j];
                s_cl -= fmaf(tt[j], __logf(p), (1.0f - tt[j]) * __logf(1.0f - p));
            }
        }
    }
    // fold cls into the shared /n_obj sum: loss_cls = (s_cl/80)/n_obj
    s_obj = fmaf(s_cl, 0.0125f, s_obj);

    // ---- wave-level reduction only (full wave converged here) ----
    float v2 = s_obj, v3 = s_cn;
    #pragma unroll
    for (int off = 32; off > 0; off >>= 1) {
        v0 += __shfl_down(v0, off, 64);
        v1 += __shfl_down(v1, off, 64);
        v2 += __shfl_down(v2, off, 64);
        v3 += __shfl_down(v3, off, 64);
    }
    if (lane == 0) {
        if (partials) {
            partials[wid] = make_float4(v0, v1, v2, v3);
        } else {
            atomicAdd(&accD[0], (double)v0);
            atomicAdd(&accD[8], (double)v1);
            atomicAdd(&accD[16], (double)v2);
            atomicAdd(&accD[24], (double)v3);
        }
    }
}

__global__ __launch_bounds__(256) void yolo_reduce(const float4* __restrict__ partials,
                                                   float* __restrict__ out_loss)
{
    __shared__ double sred[4][4];
    const int tid = threadIdx.x, wv = tid >> 6, ln = tid & 63;
    double d0 = 0, d1 = 0, d2 = 0, d3 = 0;
    for (int i = tid; i < NWAVE; i += 256) {
        float4 p = partials[i];
        d0 += (double)p.x; d1 += (double)p.y; d2 += (double)p.z; d3 += (double)p.w;
    }
    #pragma unroll
    for (int off = 32; off > 0; off >>= 1) {
        d0 += __shfl_down(d0, off, 64);
        d1 += __shfl_down(d1, off, 64);
        d2 += __shfl_down(d2, off, 64);
        d3 += __shfl_down(d3, off, 64);
    }
    if (ln == 0) { sred[wv][0] = d0; sred[wv][1] = d1; sred[wv][2] = d2; sred[wv][3] = d3; }
    __syncthreads();
    if (tid == 0) {
        double t0 = sred[0][0] + sred[1][0] + sred[2][0] + sred[3][0];
        double t1 = sred[0][1] + sred[1][1] + sred[2][1] + sred[3][1];
        double t2 = sred[0][2] + sred[1][2] + sred[2][2] + sred[3][2];
        double t3 = sred[0][3] + sred[1][3] + sred[2][3] + sred[3][3];
        double nobj = fmax(t0, 1.0), nnoobj = fmax(t1, 1.0);
        *out_loss = (float)(t2 / nobj + 100.0 * t3 / nnoobj);
    }
}

__global__ void yolo_final_atomic(const double* __restrict__ accD, float* __restrict__ out_loss)
{
    double nobj = fmax(accD[0], 1.0), nnoobj = fmax(accD[8], 1.0);
    *out_loss = (float)(accD[16] / nobj + 100.0 * accD[24] / nnoobj);
}

extern "C" void kernel_launch(void* const* d_in, const int* in_sizes, int n_in,
                              void* d_out, int out_size, void* d_ws, size_t ws_size,
                              hipStream_t stream)
{
    const float* x     = (const float*)d_in[0];
    const float* tx    = (const float*)d_in[1];
    const float* ty    = (const float*)d_in[2];
    const float* tw    = (const float*)d_in[3];
    const float* th    = (const float*)d_in[4];
    const float* tconf = (const float*)d_in[5];
    const float* tcls  = (const float*)d_in[6];
    const float* sw1   = (const float*)d_in[7];
    const int*   om    = (const int*)d_in[8];
    const int*   nm    = (const int*)d_in[9];
    const int*   img   = (const int*)d_in[10];
    float* out = (float*)d_out;

    const size_t need = (size_t)NWAVE * sizeof(float4);   // ~254 KB
    dim3 grid(NBLK);   // 4056 blocks

    if (ws_size >= need) {
        float4* partials = (float4*)d_ws;
        yolo_main<<<grid, 256, 0, stream>>>(x, tx, ty, tw, th, tconf, tcls, sw1,
                                            om, nm, img, out, partials, nullptr);
        yolo_reduce<<<1, 256, 0, stream>>>(partials, out + (out_size - 1));
    } else {
        double* accD = (double*)d_ws;
        hipMemsetAsync(d_ws, 0, 32 * sizeof(double), stream);
        yolo_main<<<grid, 256, 0, stream>>>(x, tx, ty, tw, th, tconf, tcls, sw1,
                                            om, nm, img, out, nullptr, accD);
        yolo_final_atomic<<<1, 1, 0, stream>>>(accD, out + (out_size - 1));
    }
}

// Round 9
// 57.672 us; speedup vs baseline: 1.4237x; 1.1532x over previous
//
#include <hip/hip_runtime.h>

#define NB 32
#define NA 3
#define GD 52
#define GG 2704              // 52*52
#define NC 80
#define CHN 85               // NC + 5
#define CPW 8                // cells per wave
#define WPP 338              // waves per plane = GG/CPW
#define NPLANE (NB * NA)     // 96
#define NWAVE (NPLANE * WPP) // 32448
#define WPB 4                // waves per block (256 threads)
#define NBLK (NWAVE / WPB)   // 8112
#define NXQ 170              // CPW*CHN/4 x-quads per wave
#define NTQ 160              // CPW*NC/4 tcls quads per wave
#define LXW 680              // CPW*CHN words per wave
#define AUXW 80              // 10 aux planes * CPW per wave
#define RBLK 32              // stage-A reduce blocks

// sigmoid via hardware rcp (|z| < ~7 here; validated absmax 0.25 << 44.5)
__device__ __forceinline__ float sigm_u(float u) { return __builtin_amdgcn_rcpf(u); }

__global__ __launch_bounds__(256) void yolo_main(
    const float* __restrict__ x,
    const float* __restrict__ tx, const float* __restrict__ ty,
    const float* __restrict__ tw, const float* __restrict__ th,
    const float* __restrict__ tconf, const float* __restrict__ tcls,
    const float* __restrict__ sw1,
    const int* __restrict__ om, const int* __restrict__ nm,
    const int* __restrict__ imgdim,
    float* __restrict__ out,
    float4* __restrict__ partials,     // [NWAVE]; may be null
    double* __restrict__ accD)         // fallback padded atomics
{
    __shared__ float lx_all[WPB * LXW];    // per-wave transposed tiles
    __shared__ float la_all[WPB * AUXW];   // per-wave aux tables

    const int tid  = threadIdx.x;
    const int widx = tid >> 6, lane = tid & 63;
    const int wid  = blockIdx.x * WPB + widx;
    const int plane = wid / WPP;
    const int sblk  = wid - plane * WPP;
    const int a = plane % NA, b = plane / NA;
    const int s0 = sblk * CPW;             // 32B-aligned x segment per channel
    float* lx = lx_all + widx * LXW;
    float* la = la_all + widx * AUXW;

    int iv = imgdim[0];
    float imgf = (iv > 0 && iv < 65536) ? (float)iv : __int_as_float(iv);
    const float stride = imgf / (float)GD;
    const float aw = (a == 0) ? 10.0f : ((a == 1) ? 16.0f : 33.0f);
    const float ah = (a == 0) ? 13.0f : ((a == 1) ? 30.0f : 23.0f);

    const long pbase = (long)plane * GG + s0;
    const float* xb = x + ((long)b * (NA * CHN) + a * CHN) * GG + s0;
    const float* tb = tcls + pbase * NC;

    // ---- aux: lanes 0-7 load the wave's 8 cells -> wave-local LDS table.
    //      planes: 0:tx 1:ty 2:tw 3:th 4:tconf 5:om*sw 6:nm 7:om 8:gx 9:gy
    float v0 = 0.0f, v1 = 0.0f;
    if (lane < CPW) {
        float vtx = tx[pbase + lane],    vty = ty[pbase + lane];
        float vtw = tw[pbase + lane],    vth = th[pbase + lane];
        float vtc = tconf[pbase + lane], vsw = sw1[pbase + lane];
        float vom = (float)om[pbase + lane], vnm = (float)nm[pbase + lane];
        int gcell = s0 + lane;
        int gyi = gcell / GD;
        la[0 * CPW + lane] = vtx;  la[1 * CPW + lane] = vty;
        la[2 * CPW + lane] = vtw;  la[3 * CPW + lane] = vth;
        la[4 * CPW + lane] = vtc;  la[5 * CPW + lane] = vom * vsw;
        la[6 * CPW + lane] = vnm;  la[7 * CPW + lane] = vom;
        la[8 * CPW + lane] = (float)(gcell - gyi * GD);
        la[9 * CPW + lane] = (float)gyi;
        v0 = vom; v1 = vnm;
    }

    // ---- x prefetch: all 3 quads in flight at once (12 VGPRs) ----
    float4 xr[3];
    #pragma unroll
    for (int k = 0; k < 3; ++k) {
        int q = lane + 64 * k;
        if (q < NXQ) {
            int ch = q >> 1, sq = (q & 1) << 2;   // 2 quads per channel
            xr[k] = *(const float4*)(xb + (long)ch * GG + sq);
        }
    }
    __builtin_amdgcn_wave_barrier();

    // ---- tcls gated prefetch; gate from wave-local LDS (exec-mask-safe) ----
    float4 tr[3]; float gk[3];
    #pragma unroll
    for (int k = 0; k < 3; ++k) {
        gk[k] = 0.0f;
        int q = lane + 64 * k;
        if (q < NTQ) {
            int s = q / 20, c4 = (q - s * 20) * 4;
            float g = la[7 * CPW + s];
            gk[k] = g;
            if (g != 0.0f) tr[k] = *(const float4*)(tb + s * NC + c4);
        }
    }

    float s_obj = 0.f, s_cn = 0.f, s_cl = 0.f;

    // ---- transform + losses; aux via wave-local LDS; wave-local lx store ----
    #pragma unroll
    for (int k = 0; k < 3; ++k) {
        int q = lane + 64 * k;
        if (q >= NXQ) continue;
        int ch = q >> 1, sq = (q & 1) << 2;
        float vv[4] = { xr[k].x, xr[k].y, xr[k].z, xr[k].w };
        if (ch >= 5) {
            #pragma unroll
            for (int j = 0; j < 4; ++j)
                lx[(sq + j) * CHN + ch] = sigm_u(1.0f + __expf(-vv[j]));
        } else if (ch == 0) {
            #pragma unroll
            for (int j = 0; j < 4; ++j) {
                int s = sq + j;
                float p = sigm_u(1.0f + __expf(-vv[j]));
                float d = p - la[0 * CPW + s];
                s_obj = fmaf(la[5 * CPW + s], d * d, s_obj);
                lx[s * CHN + 0] = (p + la[8 * CPW + s]) * stride;
            }
        } else if (ch == 1) {
            #pragma unroll
            for (int j = 0; j < 4; ++j) {
                int s = sq + j;
                float p = sigm_u(1.0f + __expf(-vv[j]));
                float d = p - la[1 * CPW + s];
                s_obj = fmaf(la[5 * CPW + s], d * d, s_obj);
                lx[s * CHN + 1] = (p + la[9 * CPW + s]) * stride;
            }
        } else if (ch == 2) {
            #pragma unroll
            for (int j = 0; j < 4; ++j) {
                int s = sq + j;
                float d = vv[j] - la[2 * CPW + s];
                s_obj = fmaf(la[5 * CPW + s], d * d, s_obj);
                lx[s * CHN + 2] = __expf(vv[j]) * aw;
            }
        } else if (ch == 3) {
            #pragma unroll
            for (int j = 0; j < 4; ++j) {
                int s = sq + j;
                float d = vv[j] - la[3 * CPW + s];
                s_obj = fmaf(la[5 * CPW + s], d * d, s_obj);
                lx[s * CHN + 3] = __expf(vv[j]) * ah;
            }
        } else { // ch == 4: conf BCE from logits: ln(u) + (1-t)*z, u = 1+e^-z
            #pragma unroll
            for (int j = 0; j < 4; ++j) {
                int s = sq + j;
                float z = vv[j];
                float u = 1.0f + __expf(-z);
                float p = sigm_u(u);
                float t = la[4 * CPW + s];
                float bb = fmaf(1.0f - t, z, __logf(u));
                s_obj = fmaf(la[5 * CPW + s], bb, s_obj);
                s_cn  = fmaf(la[6 * CPW + s], bb, s_cn);
                lx[s * CHN + 4] = p;
            }
        }
    }
    __builtin_amdgcn_wave_barrier();

    // ---- output: wave-local ds_read_b128 + coalesced 16B global stores ----
    float* ob = out + pbase * CHN;
    #pragma unroll
    for (int k = 0; k < 3; ++k) {
        int q = lane + 64 * k;
        if (q < NXQ) {
            float4 w4 = *(const float4*)&lx[4 * q];
            *(float4*)(ob + 4 * q) = w4;
        }
    }

    // ---- cls BCE from prefetched tcls + wave-local lx reads ----
    #pragma unroll
    for (int k = 0; k < 3; ++k) {
        if (gk[k] != 0.0f) {
            int q = lane + 64 * k;
            int s = q / 20, c4 = (q - s * 20) * 4;
            int base = s * CHN + 5 + c4;
            float tt[4] = { tr[k].x, tr[k].y, tr[k].z, tr[k].w };
            #pragma unroll
            for (int j = 0; j < 4; ++j) {
                float p = lx[base + j];
                s_cl -= fmaf(tt[j], __logf(p), (1.0f - tt[j]) * __logf(1.0f - p));
            }
        }
    }
    // fold cls into the shared /n_obj sum: loss_cls = (s_cl/80)/n_obj
    s_obj = fmaf(s_cl, 0.0125f, s_obj);

    // ---- wave-level reduction only; one float4 row per wave ----
    float v2 = s_obj, v3 = s_cn;
    #pragma unroll
    for (int off = 32; off > 0; off >>= 1) {
        v0 += __shfl_down(v0, off, 64);
        v1 += __shfl_down(v1, off, 64);
        v2 += __shfl_down(v2, off, 64);
        v3 += __shfl_down(v3, off, 64);
    }
    if (lane == 0) {
        if (partials) {
            partials[wid] = make_float4(v0, v1, v2, v3);
        } else {
            atomicAdd(&accD[0], (double)v0);
            atomicAdd(&accD[8], (double)v1);
            atomicAdd(&accD[16], (double)v2);
            atomicAdd(&accD[24], (double)v3);
        }
    }
}

// stage A: RBLK blocks, each reduces a grid-stride slice -> stage2[bid]
__global__ __launch_bounds__(256) void yolo_reduceA(const float4* __restrict__ partials,
                                                    float4* __restrict__ stage2)
{
    __shared__ float sred[4][4];
    const int tid = threadIdx.x, wv = tid >> 6, ln = tid & 63;
    float d0 = 0, d1 = 0, d2 = 0, d3 = 0;
    for (int i = blockIdx.x * 256 + tid; i < NWAVE; i += RBLK * 256) {
        float4 p = partials[i];
        d0 += p.x; d1 += p.y; d2 += p.z; d3 += p.w;
    }
    #pragma unroll
    for (int off = 32; off > 0; off >>= 1) {
        d0 += __shfl_down(d0, off, 64);
        d1 += __shfl_down(d1, off, 64);
        d2 += __shfl_down(d2, off, 64);
        d3 += __shfl_down(d3, off, 64);
    }
    if (ln == 0) { sred[wv][0] = d0; sred[wv][1] = d1; sred[wv][2] = d2; sred[wv][3] = d3; }
    __syncthreads();
    if (tid == 0)
        stage2[blockIdx.x] = make_float4(sred[0][0] + sred[1][0] + sred[2][0] + sred[3][0],
                                         sred[0][1] + sred[1][1] + sred[2][1] + sred[3][1],
                                         sred[0][2] + sred[1][2] + sred[2][2] + sred[3][2],
                                         sred[0][3] + sred[1][3] + sred[2][3] + sred[3][3]);
}

// stage B: one wave folds the RBLK rows and finalizes the loss
__global__ __launch_bounds__(64) void yolo_reduceB(const float4* __restrict__ stage2,
                                                   float* __restrict__ out_loss)
{
    const int ln = threadIdx.x;
    double d0 = 0, d1 = 0, d2 = 0, d3 = 0;
    if (ln < RBLK) {
        float4 p = stage2[ln];
        d0 = p.x; d1 = p.y; d2 = p.z; d3 = p.w;
    }
    #pragma unroll
    for (int off = 32; off > 0; off >>= 1) {
        d0 += __shfl_down(d0, off, 64);
        d1 += __shfl_down(d1, off, 64);
        d2 += __shfl_down(d2, off, 64);
        d3 += __shfl_down(d3, off, 64);
    }
    if (ln == 0) {
        double nobj = fmax(d0, 1.0), nnoobj = fmax(d1, 1.0);
        *out_loss = (float)(d2 / nobj + 100.0 * d3 / nnoobj);
    }
}

__global__ void yolo_final_atomic(const double* __restrict__ accD, float* __restrict__ out_loss)
{
    double nobj = fmax(accD[0], 1.0), nnoobj = fmax(accD[8], 1.0);
    *out_loss = (float)(accD[16] / nobj + 100.0 * accD[24] / nnoobj);
}

extern "C" void kernel_launch(void* const* d_in, const int* in_sizes, int n_in,
                              void* d_out, int out_size, void* d_ws, size_t ws_size,
                              hipStream_t stream)
{
    const float* x     = (const float*)d_in[0];
    const float* tx    = (const float*)d_in[1];
    const float* ty    = (const float*)d_in[2];
    const float* tw    = (const float*)d_in[3];
    const float* th    = (const float*)d_in[4];
    const float* tconf = (const float*)d_in[5];
    const float* tcls  = (const float*)d_in[6];
    const float* sw1   = (const float*)d_in[7];
    const int*   om    = (const int*)d_in[8];
    const int*   nm    = (const int*)d_in[9];
    const int*   img   = (const int*)d_in[10];
    float* out = (float*)d_out;

    const size_t need = (size_t)(NWAVE + RBLK) * sizeof(float4);  // ~520 KB
    dim3 grid(NBLK);   // 8112 blocks

    if (ws_size >= need) {
        float4* partials = (float4*)d_ws;
        float4* stage2   = partials + NWAVE;
        yolo_main<<<grid, 256, 0, stream>>>(x, tx, ty, tw, th, tconf, tcls, sw1,
                                            om, nm, img, out, partials, nullptr);
        yolo_reduceA<<<RBLK, 256, 0, stream>>>(partials, stage2);
        yolo_reduceB<<<1, 64, 0, stream>>>(stage2, out + (out_size - 1));
    } else {
        double* accD = (double*)d_ws;
        hipMemsetAsync(d_ws, 0, 32 * sizeof(double), stream);
        yolo_main<<<grid, 256, 0, stream>>>(x, tx, ty, tw, th, tconf, tcls, sw1,
                                            om, nm, img, out, nullptr, accD);
        yolo_final_atomic<<<1, 1, 0, stream>>>(accD, out + (out_size - 1));
    }
}

// Round 10
// 54.726 us; speedup vs baseline: 1.5003x; 1.0538x over previous
//
#include <hip/hip_runtime.h>

#define NB 32
#define NA 3
#define GD 52
#define GG 2704              // 52*52
#define NC 80
#define CHN 85               // NC + 5
#define CPW 8                // cells per wave
#define WPP 338              // waves per plane = GG/CPW
#define NPLANE (NB * NA)     // 96
#define NWAVE (NPLANE * WPP) // 32448
#define WPB 4                // waves per block (256 threads)
#define NBLK (NWAVE / WPB)   // 8112
#define NXQ 170              // CPW*CHN/4 x-quads per wave
#define NTQ 160              // CPW*NC/4 tcls quads per wave
#define LXW 680              // CPW*CHN words per wave
#define AUXW 72              // 9 aux planes * CPW per wave
#define RBLK 32              // stage-A reduce blocks
#define NEG_LN2_80 (-0.008664339757f)   // -ln2/80

// sigmoid via hardware rcp (|z| < ~7 here; validated absmax 0.25 << 44.5)
__device__ __forceinline__ float sigm_u(float u) { return __builtin_amdgcn_rcpf(u); }

__global__ __launch_bounds__(256) void yolo_main(
    const float* __restrict__ x,
    const float* __restrict__ tx, const float* __restrict__ ty,
    const float* __restrict__ tw, const float* __restrict__ th,
    const float* __restrict__ tconf, const float* __restrict__ tcls,
    const float* __restrict__ sw1,
    const int* __restrict__ om, const int* __restrict__ nm,
    const int* __restrict__ imgdim,
    float* __restrict__ out,
    float4* __restrict__ partials,     // [NWAVE]; may be null
    double* __restrict__ accD)         // fallback padded atomics
{
    __shared__ float lx_all[WPB * LXW];    // per-wave transposed tiles
    __shared__ float la_all[WPB * AUXW];   // per-wave aux tables

    const int tid  = threadIdx.x;
    const int widx = tid >> 6, lane = tid & 63;
    const int wid  = blockIdx.x * WPB + widx;
    const int plane = wid / WPP;
    const int sblk  = wid - plane * WPP;
    const int a = plane % NA, b = plane / NA;
    const int s0 = sblk * CPW;             // 32B-aligned x segment per channel
    float* lx = lx_all + widx * LXW;
    float* la = la_all + widx * AUXW;

    int iv = imgdim[0];
    float imgf = (iv > 0 && iv < 65536) ? (float)iv : __int_as_float(iv);
    const float stride = imgf / (float)GD;
    const float aw = (a == 0) ? 10.0f : ((a == 1) ? 16.0f : 33.0f);
    const float ah = (a == 0) ? 13.0f : ((a == 1) ? 30.0f : 23.0f);

    const long pbase = (long)plane * GG + s0;
    const float* xb = x + ((long)b * (NA * CHN) + a * CHN) * GG + s0;
    const float* tb = tcls + pbase * NC;

    // ---- issue x loads first (no dependencies) ----
    float4 xr[3];
    #pragma unroll
    for (int k = 0; k < 3; ++k) {
        int q = lane + 64 * k;
        if (q < NXQ) {
            int ch = q >> 1, sq = (q & 1) << 2;   // 2 quads per channel
            xr[k] = *(const float4*)(xb + (long)ch * GG + sq);
        }
    }

    // ---- aux in registers, replicated x8 (lane holds cell lane&7);
    //      8-way broadcast loads are coalesced ----
    const int sc = lane & 7;
    float r_tx = tx[pbase + sc], r_ty = ty[pbase + sc];
    float r_tw = tw[pbase + sc], r_th = th[pbase + sc];
    float r_tc = tconf[pbase + sc], r_sw = sw1[pbase + sc];
    float r_om = (float)om[pbase + sc], r_nm = (float)nm[pbase + sc];

    // ---- tcls gate via UNIFORM-FLOW shfl (exec-mask-safe) + gated issue ----
    float4 tr[3]; float gk[3];
    #pragma unroll
    for (int k = 0; k < 3; ++k) {
        gk[k] = 0.0f;
        int q = lane + 64 * k;
        if (q < NTQ) {
            int s = q / 20, c4 = (q - s * 20) * 4;
            float g = __shfl(r_om, s, 8);
            gk[k] = g;
            if (g != 0.0f) tr[k] = *(const float4*)(tb + s * NC + c4);
        }
    }

    // ---- la table for the divergent transform phase (lanes 0-7 write).
    //      planes: 0:tx 1:ty 2:tw 3:th 4:tconf 5:om*sw 6:nm 7:gx 8:gy
    if (lane < CPW) {
        int gcell = s0 + lane;
        int gyi = gcell / GD;
        la[0 * CPW + lane] = r_tx;  la[1 * CPW + lane] = r_ty;
        la[2 * CPW + lane] = r_tw;  la[3 * CPW + lane] = r_th;
        la[4 * CPW + lane] = r_tc;  la[5 * CPW + lane] = r_om * r_sw;
        la[6 * CPW + lane] = r_nm;
        la[7 * CPW + lane] = (float)(gcell - gyi * GD);
        la[8 * CPW + lane] = (float)gyi;
    }
    __builtin_amdgcn_wave_barrier();

    float s_obj = 0.f, s_cn = 0.f, s_cl2 = 0.f;

    // ---- transform + coord/conf losses; aux via wave-local LDS ----
    #pragma unroll
    for (int k = 0; k < 3; ++k) {
        int q = lane + 64 * k;
        if (q >= NXQ) continue;
        int ch = q >> 1, sq = (q & 1) << 2;
        float vv[4] = { xr[k].x, xr[k].y, xr[k].z, xr[k].w };
        if (ch >= 5) {
            #pragma unroll
            for (int j = 0; j < 4; ++j)
                lx[(sq + j) * CHN + ch] = sigm_u(1.0f + __expf(-vv[j]));
        } else if (ch == 0) {
            #pragma unroll
            for (int j = 0; j < 4; ++j) {
                int s = sq + j;
                float p = sigm_u(1.0f + __expf(-vv[j]));
                float d = p - la[0 * CPW + s];
                s_obj = fmaf(la[5 * CPW + s], d * d, s_obj);
                lx[s * CHN + 0] = (p + la[7 * CPW + s]) * stride;
            }
        } else if (ch == 1) {
            #pragma unroll
            for (int j = 0; j < 4; ++j) {
                int s = sq + j;
                float p = sigm_u(1.0f + __expf(-vv[j]));
                float d = p - la[1 * CPW + s];
                s_obj = fmaf(la[5 * CPW + s], d * d, s_obj);
                lx[s * CHN + 1] = (p + la[8 * CPW + s]) * stride;
            }
        } else if (ch == 2) {
            #pragma unroll
            for (int j = 0; j < 4; ++j) {
                int s = sq + j;
                float d = vv[j] - la[2 * CPW + s];
                s_obj = fmaf(la[5 * CPW + s], d * d, s_obj);
                lx[s * CHN + 2] = __expf(vv[j]) * aw;
            }
        } else if (ch == 3) {
            #pragma unroll
            for (int j = 0; j < 4; ++j) {
                int s = sq + j;
                float d = vv[j] - la[3 * CPW + s];
                s_obj = fmaf(la[5 * CPW + s], d * d, s_obj);
                lx[s * CHN + 3] = __expf(vv[j]) * ah;
            }
        } else { // ch == 4: conf BCE from logits: ln(u) + (1-t)*z, u = 1+e^-z
            #pragma unroll
            for (int j = 0; j < 4; ++j) {
                int s = sq + j;
                float z = vv[j];
                float u = 1.0f + __expf(-z);
                float p = sigm_u(u);
                float t = la[4 * CPW + s];
                float bb = fmaf(1.0f - t, z, __logf(u));
                s_obj = fmaf(la[5 * CPW + s], bb, s_obj);
                s_cn  = fmaf(la[6 * CPW + s], bb, s_cn);
                lx[s * CHN + 4] = p;
            }
        }
    }
    __builtin_amdgcn_wave_barrier();

    // ---- output: wave-local ds_read_b128 + coalesced 16B global stores ----
    float* ob = out + pbase * CHN;
    #pragma unroll
    for (int k = 0; k < 3; ++k) {
        int q = lane + 64 * k;
        if (q < NXQ) {
            float4 w4 = *(const float4*)&lx[4 * q];
            *(float4*)(ob + 4 * q) = w4;
        }
    }

    // ---- cls BCE in log2 form: bce_sum = -ln2 * sum(l1 + t*(l0-l1)) ----
    #pragma unroll
    for (int k = 0; k < 3; ++k) {
        if (gk[k] != 0.0f) {
            int q = lane + 64 * k;
            int s = q / 20, c4 = (q - s * 20) * 4;
            int base = s * CHN + 5 + c4;
            float tt[4] = { tr[k].x, tr[k].y, tr[k].z, tr[k].w };
            #pragma unroll
            for (int j = 0; j < 4; ++j) {
                float p  = lx[base + j];
                float l0 = __log2f(p);
                float l1 = __log2f(1.0f - p);
                s_cl2 += fmaf(tt[j], l0 - l1, l1);
            }
        }
    }
    // loss_cls contribution: (-ln2 * s_cl2 / 80) / n_obj, folded into s_obj
    s_obj = fmaf(s_cl2, NEG_LN2_80, s_obj);

    // ---- wave-level reduction only; one float4 row per wave ----
    float v0 = (lane < CPW) ? r_om : 0.0f;   // replicated x8: count once
    float v1 = (lane < CPW) ? r_nm : 0.0f;
    float v2 = s_obj, v3 = s_cn;
    #pragma unroll
    for (int off = 32; off > 0; off >>= 1) {
        v0 += __shfl_down(v0, off, 64);
        v1 += __shfl_down(v1, off, 64);
        v2 += __shfl_down(v2, off, 64);
        v3 += __shfl_down(v3, off, 64);
    }
    if (lane == 0) {
        if (partials) {
            partials[wid] = make_float4(v0, v1, v2, v3);
        } else {
            atomicAdd(&accD[0], (double)v0);
            atomicAdd(&accD[8], (double)v1);
            atomicAdd(&accD[16], (double)v2);
            atomicAdd(&accD[24], (double)v3);
        }
    }
}

// stage A: RBLK blocks, each reduces a grid-stride slice -> stage2[bid]
__global__ __launch_bounds__(256) void yolo_reduceA(const float4* __restrict__ partials,
                                                    float4* __restrict__ stage2)
{
    __shared__ float sred[4][4];
    const int tid = threadIdx.x, wv = tid >> 6, ln = tid & 63;
    float d0 = 0, d1 = 0, d2 = 0, d3 = 0;
    for (int i = blockIdx.x * 256 + tid; i < NWAVE; i += RBLK * 256) {
        float4 p = partials[i];
        d0 += p.x; d1 += p.y; d2 += p.z; d3 += p.w;
    }
    #pragma unroll
    for (int off = 32; off > 0; off >>= 1) {
        d0 += __shfl_down(d0, off, 64);
        d1 += __shfl_down(d1, off, 64);
        d2 += __shfl_down(d2, off, 64);
        d3 += __shfl_down(d3, off, 64);
    }
    if (ln == 0) { sred[wv][0] = d0; sred[wv][1] = d1; sred[wv][2] = d2; sred[wv][3] = d3; }
    __syncthreads();
    if (tid == 0)
        stage2[blockIdx.x] = make_float4(sred[0][0] + sred[1][0] + sred[2][0] + sred[3][0],
                                         sred[0][1] + sred[1][1] + sred[2][1] + sred[3][1],
                                         sred[0][2] + sred[1][2] + sred[2][2] + sred[3][2],
                                         sred[0][3] + sred[1][3] + sred[2][3] + sred[3][3]);
}

// stage B: one wave folds the RBLK rows and finalizes the loss
__global__ __launch_bounds__(64) void yolo_reduceB(const float4* __restrict__ stage2,
                                                   float* __restrict__ out_loss)
{
    const int ln = threadIdx.x;
    double d0 = 0, d1 = 0, d2 = 0, d3 = 0;
    if (ln < RBLK) {
        float4 p = stage2[ln];
        d0 = p.x; d1 = p.y; d2 = p.z; d3 = p.w;
    }
    #pragma unroll
    for (int off = 32; off > 0; off >>= 1) {
        d0 += __shfl_down(d0, off, 64);
        d1 += __shfl_down(d1, off, 64);
        d2 += __shfl_down(d2, off, 64);
        d3 += __shfl_down(d3, off, 64);
    }
    if (ln == 0) {
        double nobj = fmax(d0, 1.0), nnoobj = fmax(d1, 1.0);
        *out_loss = (float)(d2 / nobj + 100.0 * d3 / nnoobj);
    }
}

__global__ void yolo_final_atomic(const double* __restrict__ accD, float* __restrict__ out_loss)
{
    double nobj = fmax(accD[0], 1.0), nnoobj = fmax(accD[8], 1.0);
    *out_loss = (float)(accD[16] / nobj + 100.0 * accD[24] / nnoobj);
}

extern "C" void kernel_launch(void* const* d_in, const int* in_sizes, int n_in,
                              void* d_out, int out_size, void* d_ws, size_t ws_size,
                              hipStream_t stream)
{
    const float* x     = (const float*)d_in[0];
    const float* tx    = (const float*)d_in[1];
    const float* ty    = (const float*)d_in[2];
    const float* tw    = (const float*)d_in[3];
    const float* th    = (const float*)d_in[4];
    const float* tconf = (const float*)d_in[5];
    const float* tcls  = (const float*)d_in[6];
    const float* sw1   = (const float*)d_in[7];
    const int*   om    = (const int*)d_in[8];
    const int*   nm    = (const int*)d_in[9];
    const int*   img   = (const int*)d_in[10];
    float* out = (float*)d_out;

    const size_t need = (size_t)(NWAVE + RBLK) * sizeof(float4);  // ~520 KB
    dim3 grid(NBLK);   // 8112 blocks

    if (ws_size >= need) {
        float4* partials = (float4*)d_ws;
        float4* stage2   = partials + NWAVE;
        yolo_main<<<grid, 256, 0, stream>>>(x, tx, ty, tw, th, tconf, tcls, sw1,
                                            om, nm, img, out, partials, nullptr);
        yolo_reduceA<<<RBLK, 256, 0, stream>>>(partials, stage2);
        yolo_reduceB<<<1, 64, 0, stream>>>(stage2, out + (out_size - 1));
    } else {
        double* accD = (double*)d_ws;
        hipMemsetAsync(d_ws, 0, 32 * sizeof(double), stream);
        yolo_main<<<grid, 256, 0, stream>>>(x, tx, ty, tw, th, tconf, tcls, sw1,
                                            om, nm, img, out, nullptr, accD);
        yolo_final_atomic<<<1, 1, 0, stream>>>(accD, out + (out_size - 1));
    }
}

// Round 11
// 53.970 us; speedup vs baseline: 1.5213x; 1.0140x over previous
//
#include <hip/hip_runtime.h>

#define NB 32
#define NA 3
#define GD 52
#define GG 2704              // 52*52
#define NC 80
#define CHN 85               // NC + 5
#define CPW 16               // cells per wave (two 8-cell sub-passes)
#define CSW 8                // cells per sub-pass
#define WPP 169              // waves per plane = GG/CPW
#define NPLANE (NB * NA)     // 96
#define NWAVE (NPLANE * WPP) // 16224
#define WPB 4                // waves per block (256 threads)
#define NBLK (NWAVE / WPB)   // 4056
#define NXQ8 170             // CSW*CHN/4 x-quads per sub-pass
#define NTQ8 160             // CSW*NC/4 tcls quads per sub-pass
#define LXW 680              // CSW*CHN words per wave (reused across passes)
#define AUXW 144             // 9 aux planes * CPW per wave
#define RBLK 32              // stage-A reduce blocks
#define NEG_LN2_80 (-0.008664339757f)   // -ln2/80

// sigmoid via hardware rcp (|z| < ~7 here; validated absmax 0.25 << 44.5)
__device__ __forceinline__ float sigm_u(float u) { return __builtin_amdgcn_rcpf(u); }

__global__ __launch_bounds__(256) void yolo_main(
    const float* __restrict__ x,
    const float* __restrict__ tx, const float* __restrict__ ty,
    const float* __restrict__ tw, const float* __restrict__ th,
    const float* __restrict__ tconf, const float* __restrict__ tcls,
    const float* __restrict__ sw1,
    const int* __restrict__ om, const int* __restrict__ nm,
    const int* __restrict__ imgdim,
    float* __restrict__ out,
    float4* __restrict__ partials,     // [NWAVE]; may be null
    double* __restrict__ accD)         // fallback padded atomics
{
    __shared__ float lx_all[WPB * LXW];    // per-wave 8-cell transposed tile
    __shared__ float la_all[WPB * AUXW];   // per-wave 16-cell aux tables

    const int tid  = threadIdx.x;
    const int widx = tid >> 6, lane = tid & 63;
    const int wid  = blockIdx.x * WPB + widx;
    const int plane = wid / WPP;
    const int sblk  = wid - plane * WPP;
    const int a = plane % NA, b = plane / NA;
    const int s0 = sblk * CPW;             // 64B-aligned x segment per channel
    float* lx = lx_all + widx * LXW;
    float* la = la_all + widx * AUXW;

    int iv = imgdim[0];
    float imgf = (iv > 0 && iv < 65536) ? (float)iv : __int_as_float(iv);
    const float stride = imgf / (float)GD;
    const float aw = (a == 0) ? 10.0f : ((a == 1) ? 16.0f : 33.0f);
    const float ah = (a == 0) ? 13.0f : ((a == 1) ? 30.0f : 23.0f);

    const long pbase = (long)plane * GG + s0;
    const float* xb = x + ((long)b * (NA * CHN) + a * CHN) * GG + s0;
    const float* tb = tcls + pbase * NC;

    // ---- issue ALL x loads up front: both sub-tiles (6 KB/wave in flight).
    //      quad p (pass P): ch = p>>1, sq = (p&1)*4, addr = ch*GG + P*8 + sq
    float4 xrA[3], xrB[3];
    #pragma unroll
    for (int k = 0; k < 3; ++k) {
        int p = lane + 64 * k;
        if (p < NXQ8) {
            int ch = p >> 1, sq = (p & 1) << 2;
            xrA[k] = *(const float4*)(xb + (long)ch * GG + sq);
            xrB[k] = *(const float4*)(xb + (long)ch * GG + CSW + sq);
        }
    }

    // ---- aux in registers, replicated x4 (lane holds cell lane&15) ----
    const int sc = lane & 15;
    float r_tx = tx[pbase + sc], r_ty = ty[pbase + sc];
    float r_tw = tw[pbase + sc], r_th = th[pbase + sc];
    float r_tc = tconf[pbase + sc], r_sw = sw1[pbase + sc];
    float r_om = (float)om[pbase + sc], r_nm = (float)nm[pbase + sc];

    // ---- la table: 9 planes x 16 cells (lanes 0-15 write) ----
    //      planes: 0:tx 1:ty 2:tw 3:th 4:tconf 5:om*sw 6:nm 7:gx 8:gy
    if (lane < CPW) {
        int gcell = s0 + lane;
        int gyi = gcell / GD;
        la[0 * CPW + lane] = r_tx;  la[1 * CPW + lane] = r_ty;
        la[2 * CPW + lane] = r_tw;  la[3 * CPW + lane] = r_th;
        la[4 * CPW + lane] = r_tc;  la[5 * CPW + lane] = r_om * r_sw;
        la[6 * CPW + lane] = r_nm;
        la[7 * CPW + lane] = (float)(gcell - gyi * GD);
        la[8 * CPW + lane] = (float)gyi;
    }
    __builtin_amdgcn_wave_barrier();

    float s_obj = 0.f, s_cn = 0.f, s_cl2 = 0.f;
    float4 tr[3]; float gk[3];

// gate + issue tcls loads for sub-pass P (uniform-flow shfl: exec-mask-safe)
#define TCLS_ISSUE(P)                                                          \
    _Pragma("unroll")                                                          \
    for (int k = 0; k < 3; ++k) {                                              \
        gk[k] = 0.0f;                                                          \
        int q = lane + 64 * k;                                                 \
        if (q < NTQ8) {                                                        \
            int s = q / 20, c4 = (q - s * 20) * 4;                             \
            float g = __shfl(r_om, (P) * CSW + s, 16);                         \
            gk[k] = g;                                                         \
            if (g != 0.0f)                                                     \
                tr[k] = *(const float4*)(tb + ((P) * CSW + s) * NC + c4);      \
        }                                                                      \
    }

// transform sub-pass P from XR regs into lx (8-cell, [s][ch] flat)
#define TRANSFORM(P, XR)                                                       \
    _Pragma("unroll")                                                          \
    for (int k = 0; k < 3; ++k) {                                              \
        int q = lane + 64 * k;                                                 \
        if (q >= NXQ8) continue;                                               \
        int ch = q >> 1, sq = (q & 1) << 2;                                    \
        float vv[4] = { XR[k].x, XR[k].y, XR[k].z, XR[k].w };                  \
        if (ch >= 5) {                                                         \
            _Pragma("unroll")                                                  \
            for (int j = 0; j < 4; ++j)                                        \
                lx[(sq + j) * CHN + ch] = sigm_u(1.0f + __expf(-vv[j]));       \
        } else if (ch == 0) {                                                  \
            _Pragma("unroll")                                                  \
            for (int j = 0; j < 4; ++j) {                                      \
                int s = sq + j, sa = (P) * CSW + s;                            \
                float p = sigm_u(1.0f + __expf(-vv[j]));                       \
                float d = p - la[0 * CPW + sa];                                \
                s_obj = fmaf(la[5 * CPW + sa], d * d, s_obj);                  \
                lx[s * CHN + 0] = (p + la[7 * CPW + sa]) * stride;             \
            }                                                                  \
        } else if (ch == 1) {                                                  \
            _Pragma("unroll")                                                  \
            for (int j = 0; j < 4; ++j) {                                      \
                int s = sq + j, sa = (P) * CSW + s;                            \
                float p = sigm_u(1.0f + __expf(-vv[j]));                       \
                float d = p - la[1 * CPW + sa];                                \
                s_obj = fmaf(la[5 * CPW + sa], d * d, s_obj);                  \
                lx[s * CHN + 1] = (p + la[8 * CPW + sa]) * stride;             \
            }                                                                  \
        } else if (ch == 2) {                                                  \
            _Pragma("unroll")                                                  \
            for (int j = 0; j < 4; ++j) {                                      \
                int s = sq + j, sa = (P) * CSW + s;                            \
                float d = vv[j] - la[2 * CPW + sa];                            \
                s_obj = fmaf(la[5 * CPW + sa], d * d, s_obj);                  \
                lx[s * CHN + 2] = __expf(vv[j]) * aw;                          \
            }                                                                  \
        } else if (ch == 3) {                                                  \
            _Pragma("unroll")                                                  \
            for (int j = 0; j < 4; ++j) {                                      \
                int s = sq + j, sa = (P) * CSW + s;                            \
                float d = vv[j] - la[3 * CPW + sa];                            \
                s_obj = fmaf(la[5 * CPW + sa], d * d, s_obj);                  \
                lx[s * CHN + 3] = __expf(vv[j]) * ah;                          \
            }                                                                  \
        } else {                                                               \
            _Pragma("unroll")                                                  \
            for (int j = 0; j < 4; ++j) {                                      \
                int s = sq + j, sa = (P) * CSW + s;                            \
                float z = vv[j];                                               \
                float u = 1.0f + __expf(-z);                                   \
                float p = sigm_u(u);                                           \
                float t = la[4 * CPW + sa];                                    \
                float bb = fmaf(1.0f - t, z, __logf(u));                       \
                s_obj = fmaf(la[5 * CPW + sa], bb, s_obj);                     \
                s_cn  = fmaf(la[6 * CPW + sa], bb, s_cn);                      \
                lx[s * CHN + 4] = p;                                           \
            }                                                                  \
        }                                                                      \
    }

// store-out sub-pass P (ds_read_b128 + coalesced 16B global stores)
#define STORE_OUT(P)                                                           \
    {                                                                          \
        float* ob = out + (pbase + (P) * CSW) * CHN;                           \
        _Pragma("unroll")                                                      \
        for (int k = 0; k < 3; ++k) {                                          \
            int q = lane + 64 * k;                                             \
            if (q < NXQ8) {                                                    \
                float4 w4 = *(const float4*)&lx[4 * q];                        \
                *(float4*)(ob + 4 * q) = w4;                                   \
            }                                                                  \
        }                                                                      \
    }

// cls BCE sub-pass (log2 form), from tr/gk + lx reads
#define CLS_BCE()                                                              \
    _Pragma("unroll")                                                          \
    for (int k = 0; k < 3; ++k) {                                              \
        if (gk[k] != 0.0f) {                                                   \
            int q = lane + 64 * k;                                             \
            int s = q / 20, c4 = (q - s * 20) * 4;                             \
            int base = s * CHN + 5 + c4;                                       \
            float tt[4] = { tr[k].x, tr[k].y, tr[k].z, tr[k].w };              \
            _Pragma("unroll")                                                  \
            for (int j = 0; j < 4; ++j) {                                      \
                float p  = lx[base + j];                                       \
                float l0 = __log2f(p);                                         \
                float l1 = __log2f(1.0f - p);                                  \
                s_cl2 += fmaf(tt[j], l0 - l1, l1);                             \
            }                                                                  \
        }                                                                      \
    }

    // ---- sub-pass A ----
    TCLS_ISSUE(0)
    TRANSFORM(0, xrA)
    __builtin_amdgcn_wave_barrier();
    STORE_OUT(0)
    CLS_BCE()
    __builtin_amdgcn_wave_barrier();

    // ---- sub-pass B (lx reuse is safe: same-wave DS ops are in-order) ----
    TCLS_ISSUE(1)
    TRANSFORM(1, xrB)
    __builtin_amdgcn_wave_barrier();
    STORE_OUT(1)
    CLS_BCE()

    // loss_cls contribution: (-ln2 * s_cl2 / 80) / n_obj, folded into s_obj
    s_obj = fmaf(s_cl2, NEG_LN2_80, s_obj);

    // ---- wave-level reduction only; one float4 row per wave ----
    float v0 = (lane < CPW) ? r_om : 0.0f;   // replicated x4: count once
    float v1 = (lane < CPW) ? r_nm : 0.0f;
    float v2 = s_obj, v3 = s_cn;
    #pragma unroll
    for (int off = 32; off > 0; off >>= 1) {
        v0 += __shfl_down(v0, off, 64);
        v1 += __shfl_down(v1, off, 64);
        v2 += __shfl_down(v2, off, 64);
        v3 += __shfl_down(v3, off, 64);
    }
    if (lane == 0) {
        if (partials) {
            partials[wid] = make_float4(v0, v1, v2, v3);
        } else {
            atomicAdd(&accD[0], (double)v0);
            atomicAdd(&accD[8], (double)v1);
            atomicAdd(&accD[16], (double)v2);
            atomicAdd(&accD[24], (double)v3);
        }
    }
}

// stage A: RBLK blocks, each reduces a grid-stride slice -> stage2[bid]
__global__ __launch_bounds__(256) void yolo_reduceA(const float4* __restrict__ partials,
                                                    float4* __restrict__ stage2)
{
    __shared__ float sred[4][4];
    const int tid = threadIdx.x, wv = tid >> 6, ln = tid & 63;
    float d0 = 0, d1 = 0, d2 = 0, d3 = 0;
    for (int i = blockIdx.x * 256 + tid; i < NWAVE; i += RBLK * 256) {
        float4 p = partials[i];
        d0 += p.x; d1 += p.y; d2 += p.z; d3 += p.w;
    }
    #pragma unroll
    for (int off = 32; off > 0; off >>= 1) {
        d0 += __shfl_down(d0, off, 64);
        d1 += __shfl_down(d1, off, 64);
        d2 += __shfl_down(d2, off, 64);
        d3 += __shfl_down(d3, off, 64);
    }
    if (ln == 0) { sred[wv][0] = d0; sred[wv][1] = d1; sred[wv][2] = d2; sred[wv][3] = d3; }
    __syncthreads();
    if (tid == 0)
        stage2[blockIdx.x] = make_float4(sred[0][0] + sred[1][0] + sred[2][0] + sred[3][0],
                                         sred[0][1] + sred[1][1] + sred[2][1] + sred[3][1],
                                         sred[0][2] + sred[1][2] + sred[2][2] + sred[3][2],
                                         sred[0][3] + sred[1][3] + sred[2][3] + sred[3][3]);
}

// stage B: one wave folds the RBLK rows and finalizes the loss
__global__ __launch_bounds__(64) void yolo_reduceB(const float4* __restrict__ stage2,
                                                   float* __restrict__ out_loss)
{
    const int ln = threadIdx.x;
    double d0 = 0, d1 = 0, d2 = 0, d3 = 0;
    if (ln < RBLK) {
        float4 p = stage2[ln];
        d0 = p.x; d1 = p.y; d2 = p.z; d3 = p.w;
    }
    #pragma unroll
    for (int off = 32; off > 0; off >>= 1) {
        d0 += __shfl_down(d0, off, 64);
        d1 += __shfl_down(d1, off, 64);
        d2 += __shfl_down(d2, off, 64);
        d3 += __shfl_down(d3, off, 64);
    }
    if (ln == 0) {
        double nobj = fmax(d0, 1.0), nnoobj = fmax(d1, 1.0);
        *out_loss = (float)(d2 / nobj + 100.0 * d3 / nnoobj);
    }
}

__global__ void yolo_final_atomic(const double* __restrict__ accD, float* __restrict__ out_loss)
{
    double nobj = fmax(accD[0], 1.0), nnoobj = fmax(accD[8], 1.0);
    *out_loss = (float)(accD[16] / nobj + 100.0 * accD[24] / nnoobj);
}

extern "C" void kernel_launch(void* const* d_in, const int* in_sizes, int n_in,
                              void* d_out, int out_size, void* d_ws, size_t ws_size,
                              hipStream_t stream)
{
    const float* x     = (const float*)d_in[0];
    const float* tx    = (const float*)d_in[1];
    const float* ty    = (const float*)d_in[2];
    const float* tw    = (const float*)d_in[3];
    const float* th    = (const float*)d_in[4];
    const float* tconf = (const float*)d_in[5];
    const float* tcls  = (const float*)d_in[6];
    const float* sw1   = (const float*)d_in[7];
    const int*   om    = (const int*)d_in[8];
    const int*   nm    = (const int*)d_in[9];
    const int*   img   = (const int*)d_in[10];
    float* out = (float*)d_out;

    const size_t need = (size_t)(NWAVE + RBLK) * sizeof(float4);  // ~260 KB
    dim3 grid(NBLK);   // 4056 blocks

    if (ws_size >= need) {
        float4* partials = (float4*)d_ws;
        float4* stage2   = partials + NWAVE;
        yolo_main<<<grid, 256, 0, stream>>>(x, tx, ty, tw, th, tconf, tcls, sw1,
                                            om, nm, img, out, partials, nullptr);
        yolo_reduceA<<<RBLK, 256, 0, stream>>>(partials, stage2);
        yolo_reduceB<<<1, 64, 0, stream>>>(stage2, out + (out_size - 1));
    } else {
        double* accD = (double*)d_ws;
        hipMemsetAsync(d_ws, 0, 32 * sizeof(double), stream);
        yolo_main<<<grid, 256, 0, stream>>>(x, tx, ty, tw, th, tconf, tcls, sw1,
                                            om, nm, img, out, nullptr, accD);
        yolo_final_atomic<<<1, 1, 0, stream>>>(accD, out + (out_size - 1));
    }
}